// Round 16
// baseline (39.715 us; speedup 1.0000x reference)
//
#include <hip/hip_runtime.h>
#include <math.h>

#define NTOT 16384
#define KK 16
#define DD 16
#define NPAIR 136   // upper-tri incl diag of 16x16

#define NPREP 9     // prep blocks; each: full phase A + 1 pair per 16-lane group
#define NMAIN 1024  // main blocks; 16 samples each (1 tile) -> max parallelism

// ---- ws layout (bytes) ----
#define WS_RHS   0          // float[256]     rhs_k
#define WS_WP    1024       // float[16*137]  W_k packed lower, stride 137
#define WS_LCS   9792       // float[136]     lC packed (+ln2 offdiag)
#define WS_END   10336

#define LN2PI 1.8378770664093454836f

#define SROW 17             // padded LDS row stride -> conflict-free
#define SMAT (SROW * DD)

// Dual right-looking Cholesky: factor TWO independent SPD matrices (row-per-lane)
// in one interleaved chain so their shfl latencies overlap.
__device__ __forceinline__ void chol16_rl2(float* Ms, float* Ma, int r,
                                           float* dinvS, float* dinvA,
                                           float& ldS, float& ldA) {
  float ls = 0.0f, la = 0.0f;
  #pragma unroll
  for (int c = 0; c < DD; c++) {
    float d2s = __shfl(Ms[c], c, 16);
    float d2a = __shfl(Ma[c], c, 16);
    ls += __logf(d2s);
    la += __logf(d2a);
    float dis = rsqrtf(d2s), dia = rsqrtf(d2a);
    dinvS[c] = dis; dinvA[c] = dia;
    float vs = Ms[c] * dis, va = Ma[c] * dia;
    Ms[c] = vs; Ma[c] = va;
    #pragma unroll
    for (int c2 = c + 1; c2 < DD; c2++) {
      Ms[c2] = fmaf(-vs, __shfl(vs, c2, 16), Ms[c2]);
      Ma[c2] = fmaf(-va, __shfl(va, c2, 16), Ma[c2]);
    }
  }
  ldS = ls; ldA = la;
}

// Dual forward solve G y = b for two systems, |y|^2 returned for each.
__device__ __forceinline__ void solve16_2(const float* Gs, const float* Ga, int r,
                                          const float* dinvS, const float* dinvA,
                                          float bs, float ba,
                                          float& qs, float& qa) {
  float accS = bs, accA = ba, s = 0.0f, a = 0.0f;
  #pragma unroll
  for (int m = 0; m < DD; m++) {
    float ys = __shfl(accS, m, 16) * dinvS[m];
    float ya = __shfl(accA, m, 16) * dinvA[m];
    s = fmaf(ys, ys, s);
    a = fmaf(ya, ya, a);
    if (r > m) {
      accS = fmaf(-Gs[m], ys, accS);
      accA = fmaf(-Ga[m], ya, accA);
    }
  }
  qs = s; qa = a;
}

// Single right-looking Cholesky (phase A).
__device__ __forceinline__ float chol16_rl(float* Mr, int r, float* dinvv) {
  float ld = 0.0f;
  #pragma unroll
  for (int c = 0; c < DD; c++) {
    float d2 = __shfl(Mr[c], c, 16);
    ld += __logf(d2);
    float dinv = rsqrtf(d2);
    dinvv[c] = dinv;
    float v = Mr[c] * dinv;
    Mr[c] = v;
    #pragma unroll
    for (int c2 = c + 1; c2 < DD; c2++)
      Mr[c2] = fmaf(-v, __shfl(v, c2, 16), Mr[c2]);
  }
  return ld;
}

// ---------------- K1: 9 blocks; redundant phase A + 1 pair per 16-lane group ----
__global__ __launch_bounds__(256, 1) void gm_prep(const float* __restrict__ mu,
                                                  const float* __restrict__ L,
                                                  const float* __restrict__ wts,
                                                  char* __restrict__ wsb,
                                                  float* __restrict__ out) {
  __shared__ float sSig[KK * SMAT];   // Sigma rows, stride 17
  __shared__ float sA[KK * SMAT];     // A rows, stride 17
  __shared__ float sR[256];

  const int tid = threadIdx.x;
  const int k = tid >> 4;
  const int r = tid & 15;

  if (blockIdx.x == 0 && tid == 0) out[0] = 0.0f;   // zero accumulator for K2

  // ---- phase A: 16 lanes per component ----
  const float* Lk = L + k * DD * DD;
  float Lx[DD];
  #pragma unroll
  for (int b = 0; b < DD; b++) Lx[b] = (b <= r) ? Lk[r * DD + b] : 0.0f;

  float Ar[DD];   // A row r; becomes G in place
  #pragma unroll
  for (int c = 0; c < DD; c++) {
    float s = (r == c) ? 1.0f : 0.0f;
    #pragma unroll
    for (int b = 0; b <= c; b++)
      s = fmaf(Lx[b], __shfl(Lx[b], c, 16), s);
    Ar[c] = s;
    sA[k * SMAT + r * SROW + c] = s;
  }

  float dinvv[DD];
  chol16_rl(Ar, r, dinvv);            // Ar now holds G rows

  // W = G^{-1}, right-looking column solve: lane r holds COLUMN r of W.
  float Wc[DD];
  {
    float acc[DD];
    #pragma unroll
    for (int m = 0; m < DD; m++) acc[m] = (r == m) ? 1.0f : 0.0f;
    #pragma unroll
    for (int m = 0; m < DD; m++) {
      float w = acc[m] * dinvv[m];    // W[m][r]; 0 for m<r automatically
      Wc[m] = w;
      #pragma unroll
      for (int rr = m + 1; rr < DD; rr++)
        acc[rr] = fmaf(-__shfl(Ar[m], rr, 16), w, acc[rr]);  // independent shfls
    }
  }
  if (blockIdx.x == 0) {
    float* Wout = (float*)(wsb + WS_WP) + k * 137;
    #pragma unroll
    for (int rr = 0; rr < DD; rr++)
      if (rr >= r) Wout[rr * (rr + 1) / 2 + r] = Wc[rr];
  }

  // Sigma row r = dot(W col r, W col b)
  float Sig[DD];
  #pragma unroll
  for (int b = 0; b < DD; b++) {
    float s = 0.0f;
    #pragma unroll
    for (int rr = 0; rr < DD; rr++)
      s = fmaf(Wc[rr], __shfl(Wc[rr], b, 16), s);
    Sig[b] = s;
    sSig[k * SMAT + r * SROW + b] = s;
  }

  // rhs[r] = dot(Sigma row r, mu_k)
  {
    float muv = mu[k * DD + r];
    float s = 0.0f;
    #pragma unroll
    for (int b = 0; b < DD; b++)
      s = fmaf(Sig[b], __shfl(muv, b, 16), s);
    sR[k * DD + r] = s;
    if (blockIdx.x == 0) ((float*)(wsb + WS_RHS))[k * DD + r] = s;
  }
  __syncthreads();

  // ---- phase B: one pair per 16-lane group; dual interleaved chol+solve ----
  const int p = blockIdx.x * 16 + k;
  if (p >= NPAIR) return;
  int i = 0, rem = p;
  while (rem >= (KK - i)) { rem -= (KK - i); i++; }
  const int j = i + rem;

  float Ms[DD], Ma[DD], dvS[DD], dvA[DD];
  #pragma unroll
  for (int c = 0; c < DD; c++) {
    Ms[c] = sSig[i * SMAT + r * SROW + c] + sSig[j * SMAT + r * SROW + c];
    Ma[c] = sA[i * SMAT + r * SROW + c] + sA[j * SMAT + r * SROW + c];
  }
  float ldS, ldA;
  chol16_rl2(Ms, Ma, r, dvS, dvA, ldS, ldA);

  float cq, q;
  solve16_2(Ms, Ma, r, dvS, dvA,
            sR[i * DD + r] + sR[j * DD + r],
            mu[i * DD + r] - mu[j * DD + r], cq, q);

  if (r == 0) {
    float lC = -0.5f * q - 0.5f * ldA + 0.5f * ldS - (float)DD * LN2PI
               + __logf(wts[i]) + __logf(wts[j]) - 0.5f * cq;
    if (i < j) lC += 0.69314718056f;   // symmetric pair counted twice
    ((float*)(wsb + WS_LCS))[p] = lC;
  }
}

// ---------------- K2: 1024 blocks x 16 samples; fire-and-forget atomic out ----
__global__ __launch_bounds__(256) void gm_main(const float* __restrict__ X,
                                               char* __restrict__ wsb,
                                               float* __restrict__ out) {
  __shared__ float sW[KK * 137];
  __shared__ float sR[KK * 17];
  __shared__ float sLC[NPAIR];
  __shared__ unsigned char sIJ[NPAIR];
  __shared__ float sX[256];
  __shared__ float sE[16 * 17];
  __shared__ double sD[16];

  const int tid = threadIdx.x;
  const int s = tid >> 4;
  const int r = tid & 15;

  {
    const float* Wp = (const float*)(wsb + WS_WP);
    for (int idx = tid; idx < KK * 137; idx += 256) sW[idx] = Wp[idx];
    const float* Rf = (const float*)(wsb + WS_RHS);
    sR[s * 17 + r] = Rf[tid];
    const float* lc = (const float*)(wsb + WS_LCS);
    if (tid < NPAIR) {
      sLC[tid] = lc[tid];
      int i = 0, rem = tid;
      while (rem >= (KK - i)) { rem -= (KK - i); i++; }
      sIJ[tid] = (unsigned char)((i << 4) | (i + rem));
    }
    if (tid < 64)
      ((float4*)sX)[tid] = ((const float4*)(X + (size_t)blockIdx.x * 256))[tid];
  }
  __syncthreads();

  float x[DD];
  {
    float4 b0 = ((const float4*)sX)[s * 4 + 0];
    float4 b1 = ((const float4*)sX)[s * 4 + 1];
    float4 b2 = ((const float4*)sX)[s * 4 + 2];
    float4 b3 = ((const float4*)sX)[s * 4 + 3];
    x[0]=b0.x; x[1]=b0.y; x[2]=b0.z; x[3]=b0.w;
    x[4]=b1.x; x[5]=b1.y; x[6]=b1.z; x[7]=b1.w;
    x[8]=b2.x; x[9]=b2.y; x[10]=b2.z; x[11]=b2.w;
    x[12]=b3.x; x[13]=b3.y; x[14]=b3.z; x[15]=b3.w;
  }

  // e_r = h - g/2 for component r, sample s
  {
    const float* Wk = &sW[r * 137];
    float g = 0.0f;
    #pragma unroll
    for (int rr = 0; rr < DD; rr++) {
      float y = 0.0f;
      #pragma unroll
      for (int c = 0; c <= rr; c++) y = fmaf(Wk[rr * (rr + 1) / 2 + c], x[c], y);
      g = fmaf(y, y, g);
    }
    float h = 0.0f;
    #pragma unroll
    for (int d = 0; d < DD; d++) h = fmaf(sR[r * 17 + d], x[d], h);
    sE[s * 17 + r] = fmaf(-0.5f, g, h);
  }
  __syncthreads();

  // pairs: 8-9 per lane; two-pass log-sum-exp, width-16 reductions
  float val[9];
  float T = -3.0e38f;
  #pragma unroll
  for (int t = 0; t < 9; t++) {
    int p = t * 16 + r;
    if (t < 8 || r < 8) {
      int ij = sIJ[p];
      val[t] = sLC[p] + sE[s * 17 + (ij >> 4)] + sE[s * 17 + (ij & 15)];
    } else {
      val[t] = -3.0e38f;
    }
    T = fmaxf(T, val[t]);
  }
  #pragma unroll
  for (int w = 1; w < 16; w <<= 1) T = fmaxf(T, __shfl_xor(T, w, 16));

  float sum = 0.0f;
  #pragma unroll
  for (int t = 0; t < 9; t++) sum += __expf(val[t] - T);
  #pragma unroll
  for (int w = 1; w < 16; w <<= 1) sum += __shfl_xor(sum, w, 16);

  if (r == 0) sD[s] = (double)(T + __logf(sum));
  __syncthreads();
  if (tid == 0) {
    double acc = 0.0;
    #pragma unroll
    for (int m = 0; m < 16; m++) acc += sD[m];
    // fire-and-forget: no fence, no counter, result unused -> non-returning atomic
    atomicAdd(out, (float)(acc * (1.0 / 16384.0)));
  }
}

extern "C" void kernel_launch(void* const* d_in, const int* in_sizes, int n_in,
                              void* d_out, int out_size, void* d_ws, size_t ws_size,
                              hipStream_t stream) {
  const float* X   = (const float*)d_in[0];
  const float* mu  = (const float*)d_in[1];
  const float* L   = (const float*)d_in[2];
  const float* wts = (const float*)d_in[3];
  char* wsb = (char*)d_ws;
  if (ws_size < WS_END) return;

  hipLaunchKernelGGL(gm_prep, dim3(NPREP), dim3(256), 0, stream, mu, L, wts, wsb,
                     (float*)d_out);
  hipLaunchKernelGGL(gm_main, dim3(NMAIN), dim3(256), 0, stream, X, wsb,
                     (float*)d_out);
}

// Round 17
// 31.446 us; speedup vs baseline: 1.2630x; 1.2630x over previous
//
#include <hip/hip_runtime.h>
#include <math.h>

#define NTOT 16384
#define KK 16
#define DD 16
#define NPAIR 136   // upper-tri incl diag of 16x16

#define NPREP 9     // prep blocks; each: full phase A + 1 pair per 16-lane group
#define NMAIN 1024  // main blocks; 16 samples each (1 tile) -> max parallelism

// ---- ws layout (bytes) ----
#define WS_RHS   0          // float[256]     rhs_k
#define WS_WP    1024       // float[16*137]  W_k packed lower, stride 137
#define WS_LCS   9792       // float[136]     lC packed (+ln2 offdiag)
#define WS_PART  10336      // double[1024]   block partials (8-aligned)
#define WS_END   18528

#define LN2PI 1.8378770664093454836f

#define SROW 17             // padded LDS row stride -> conflict-free
#define SMAT (SROW * DD)

// Dual right-looking Cholesky: factor TWO independent SPD matrices (row-per-lane)
// in one interleaved chain so their shfl latencies overlap.
__device__ __forceinline__ void chol16_rl2(float* Ms, float* Ma, int r,
                                           float* dinvS, float* dinvA,
                                           float& ldS, float& ldA) {
  float ls = 0.0f, la = 0.0f;
  #pragma unroll
  for (int c = 0; c < DD; c++) {
    float d2s = __shfl(Ms[c], c, 16);
    float d2a = __shfl(Ma[c], c, 16);
    ls += __logf(d2s);
    la += __logf(d2a);
    float dis = rsqrtf(d2s), dia = rsqrtf(d2a);
    dinvS[c] = dis; dinvA[c] = dia;
    float vs = Ms[c] * dis, va = Ma[c] * dia;
    Ms[c] = vs; Ma[c] = va;
    #pragma unroll
    for (int c2 = c + 1; c2 < DD; c2++) {
      Ms[c2] = fmaf(-vs, __shfl(vs, c2, 16), Ms[c2]);
      Ma[c2] = fmaf(-va, __shfl(va, c2, 16), Ma[c2]);
    }
  }
  ldS = ls; ldA = la;
}

// Dual forward solve G y = b for two systems, |y|^2 returned for each.
__device__ __forceinline__ void solve16_2(const float* Gs, const float* Ga, int r,
                                          const float* dinvS, const float* dinvA,
                                          float bs, float ba,
                                          float& qs, float& qa) {
  float accS = bs, accA = ba, s = 0.0f, a = 0.0f;
  #pragma unroll
  for (int m = 0; m < DD; m++) {
    float ys = __shfl(accS, m, 16) * dinvS[m];
    float ya = __shfl(accA, m, 16) * dinvA[m];
    s = fmaf(ys, ys, s);
    a = fmaf(ya, ya, a);
    if (r > m) {
      accS = fmaf(-Gs[m], ys, accS);
      accA = fmaf(-Ga[m], ya, accA);
    }
  }
  qs = s; qa = a;
}

// Single right-looking Cholesky (phase A).
__device__ __forceinline__ float chol16_rl(float* Mr, int r, float* dinvv) {
  float ld = 0.0f;
  #pragma unroll
  for (int c = 0; c < DD; c++) {
    float d2 = __shfl(Mr[c], c, 16);
    ld += __logf(d2);
    float dinv = rsqrtf(d2);
    dinvv[c] = dinv;
    float v = Mr[c] * dinv;
    Mr[c] = v;
    #pragma unroll
    for (int c2 = c + 1; c2 < DD; c2++)
      Mr[c2] = fmaf(-v, __shfl(v, c2, 16), Mr[c2]);
  }
  return ld;
}

// ---------------- K1: 9 blocks; redundant phase A + 1 pair per 16-lane group ----
__global__ __launch_bounds__(256, 1) void gm_prep(const float* __restrict__ mu,
                                                  const float* __restrict__ L,
                                                  const float* __restrict__ wts,
                                                  char* __restrict__ wsb) {
  __shared__ float sSig[KK * SMAT];   // Sigma rows, stride 17
  __shared__ float sA[KK * SMAT];     // A rows, stride 17
  __shared__ float sR[256];

  const int tid = threadIdx.x;
  const int k = tid >> 4;
  const int r = tid & 15;

  // ---- phase A: 16 lanes per component ----
  const float* Lk = L + k * DD * DD;
  float Lx[DD];
  #pragma unroll
  for (int b = 0; b < DD; b++) Lx[b] = (b <= r) ? Lk[r * DD + b] : 0.0f;

  float Ar[DD];   // A row r; becomes G in place
  #pragma unroll
  for (int c = 0; c < DD; c++) {
    float s = (r == c) ? 1.0f : 0.0f;
    #pragma unroll
    for (int b = 0; b <= c; b++)
      s = fmaf(Lx[b], __shfl(Lx[b], c, 16), s);
    Ar[c] = s;
    sA[k * SMAT + r * SROW + c] = s;
  }

  float dinvv[DD];
  chol16_rl(Ar, r, dinvv);            // Ar now holds G rows

  // W = G^{-1}, right-looking column solve: lane r holds COLUMN r of W.
  float Wc[DD];
  {
    float acc[DD];
    #pragma unroll
    for (int m = 0; m < DD; m++) acc[m] = (r == m) ? 1.0f : 0.0f;
    #pragma unroll
    for (int m = 0; m < DD; m++) {
      float w = acc[m] * dinvv[m];    // W[m][r]; 0 for m<r automatically
      Wc[m] = w;
      #pragma unroll
      for (int rr = m + 1; rr < DD; rr++)
        acc[rr] = fmaf(-__shfl(Ar[m], rr, 16), w, acc[rr]);  // independent shfls
    }
  }
  if (blockIdx.x == 0) {
    float* Wout = (float*)(wsb + WS_WP) + k * 137;
    #pragma unroll
    for (int rr = 0; rr < DD; rr++)
      if (rr >= r) Wout[rr * (rr + 1) / 2 + r] = Wc[rr];
  }

  // Sigma row r = dot(W col r, W col b)
  float Sig[DD];
  #pragma unroll
  for (int b = 0; b < DD; b++) {
    float s = 0.0f;
    #pragma unroll
    for (int rr = 0; rr < DD; rr++)
      s = fmaf(Wc[rr], __shfl(Wc[rr], b, 16), s);
    Sig[b] = s;
    sSig[k * SMAT + r * SROW + b] = s;
  }

  // rhs[r] = dot(Sigma row r, mu_k)
  {
    float muv = mu[k * DD + r];
    float s = 0.0f;
    #pragma unroll
    for (int b = 0; b < DD; b++)
      s = fmaf(Sig[b], __shfl(muv, b, 16), s);
    sR[k * DD + r] = s;
    if (blockIdx.x == 0) ((float*)(wsb + WS_RHS))[k * DD + r] = s;
  }
  __syncthreads();

  // ---- phase B: one pair per 16-lane group; dual interleaved chol+solve ----
  const int p = blockIdx.x * 16 + k;
  if (p >= NPAIR) return;
  int i = 0, rem = p;
  while (rem >= (KK - i)) { rem -= (KK - i); i++; }
  const int j = i + rem;

  float Ms[DD], Ma[DD], dvS[DD], dvA[DD];
  #pragma unroll
  for (int c = 0; c < DD; c++) {
    Ms[c] = sSig[i * SMAT + r * SROW + c] + sSig[j * SMAT + r * SROW + c];
    Ma[c] = sA[i * SMAT + r * SROW + c] + sA[j * SMAT + r * SROW + c];
  }
  float ldS, ldA;
  chol16_rl2(Ms, Ma, r, dvS, dvA, ldS, ldA);

  float cq, q;
  solve16_2(Ms, Ma, r, dvS, dvA,
            sR[i * DD + r] + sR[j * DD + r],
            mu[i * DD + r] - mu[j * DD + r], cq, q);

  if (r == 0) {
    float lC = -0.5f * q - 0.5f * ldA + 0.5f * ldS - (float)DD * LN2PI
               + __logf(wts[i]) + __logf(wts[j]) - 0.5f * cq;
    if (i < j) lC += 0.69314718056f;   // symmetric pair counted twice
    ((float*)(wsb + WS_LCS))[p] = lC;
  }
}

// ---------------- K2: 1024 blocks x 16 samples (1 tile, max parallelism) ------
__global__ __launch_bounds__(256) void gm_main(const float* __restrict__ X,
                                               char* __restrict__ wsb) {
  __shared__ float sW[KK * 137];
  __shared__ float sR[KK * 17];
  __shared__ float sLC[NPAIR];
  __shared__ unsigned char sIJ[NPAIR];
  __shared__ float sX[256];
  __shared__ float sE[16 * 17];
  __shared__ double sD[16];

  const int tid = threadIdx.x;
  const int s = tid >> 4;
  const int r = tid & 15;

  {
    const float* Wp = (const float*)(wsb + WS_WP);
    for (int idx = tid; idx < KK * 137; idx += 256) sW[idx] = Wp[idx];
    const float* Rf = (const float*)(wsb + WS_RHS);
    sR[s * 17 + r] = Rf[tid];
    const float* lc = (const float*)(wsb + WS_LCS);
    if (tid < NPAIR) {
      sLC[tid] = lc[tid];
      int i = 0, rem = tid;
      while (rem >= (KK - i)) { rem -= (KK - i); i++; }
      sIJ[tid] = (unsigned char)((i << 4) | (i + rem));
    }
    if (tid < 64)
      ((float4*)sX)[tid] = ((const float4*)(X + (size_t)blockIdx.x * 256))[tid];
  }
  __syncthreads();

  float x[DD];
  {
    float4 b0 = ((const float4*)sX)[s * 4 + 0];
    float4 b1 = ((const float4*)sX)[s * 4 + 1];
    float4 b2 = ((const float4*)sX)[s * 4 + 2];
    float4 b3 = ((const float4*)sX)[s * 4 + 3];
    x[0]=b0.x; x[1]=b0.y; x[2]=b0.z; x[3]=b0.w;
    x[4]=b1.x; x[5]=b1.y; x[6]=b1.z; x[7]=b1.w;
    x[8]=b2.x; x[9]=b2.y; x[10]=b2.z; x[11]=b2.w;
    x[12]=b3.x; x[13]=b3.y; x[14]=b3.z; x[15]=b3.w;
  }

  // e_r = h - g/2 for component r, sample s
  {
    const float* Wk = &sW[r * 137];
    float g = 0.0f;
    #pragma unroll
    for (int rr = 0; rr < DD; rr++) {
      float y = 0.0f;
      #pragma unroll
      for (int c = 0; c <= rr; c++) y = fmaf(Wk[rr * (rr + 1) / 2 + c], x[c], y);
      g = fmaf(y, y, g);
    }
    float h = 0.0f;
    #pragma unroll
    for (int d = 0; d < DD; d++) h = fmaf(sR[r * 17 + d], x[d], h);
    sE[s * 17 + r] = fmaf(-0.5f, g, h);
  }
  __syncthreads();

  // pairs: 8-9 per lane; two-pass log-sum-exp, width-16 reductions
  float val[9];
  float T = -3.0e38f;
  #pragma unroll
  for (int t = 0; t < 9; t++) {
    int p = t * 16 + r;
    if (t < 8 || r < 8) {
      int ij = sIJ[p];
      val[t] = sLC[p] + sE[s * 17 + (ij >> 4)] + sE[s * 17 + (ij & 15)];
    } else {
      val[t] = -3.0e38f;
    }
    T = fmaxf(T, val[t]);
  }
  #pragma unroll
  for (int w = 1; w < 16; w <<= 1) T = fmaxf(T, __shfl_xor(T, w, 16));

  float sum = 0.0f;
  #pragma unroll
  for (int t = 0; t < 9; t++) sum += __expf(val[t] - T);
  #pragma unroll
  for (int w = 1; w < 16; w <<= 1) sum += __shfl_xor(sum, w, 16);

  if (r == 0) sD[s] = (double)(T + __logf(sum));
  __syncthreads();
  if (tid == 0) {
    double acc = 0.0;
    #pragma unroll
    for (int m = 0; m < 16; m++) acc += sD[m];
    ((double*)(wsb + WS_PART))[blockIdx.x] = acc;
  }
}

// ---------------- K3: reduce 1024 partials, single 64-lane wave ----------------
__global__ __launch_bounds__(64) void gm_fin(const double* __restrict__ part,
                                             float* __restrict__ out) {
  int t = threadIdx.x;
  double v = 0.0;
  #pragma unroll
  for (int m = 0; m < 16; m++) v += part[t + m * 64];
  #pragma unroll
  for (int off = 32; off > 0; off >>= 1) v += __shfl_down(v, off);
  if (t == 0) out[0] = (float)(v * (1.0 / 16384.0));
}

extern "C" void kernel_launch(void* const* d_in, const int* in_sizes, int n_in,
                              void* d_out, int out_size, void* d_ws, size_t ws_size,
                              hipStream_t stream) {
  const float* X   = (const float*)d_in[0];
  const float* mu  = (const float*)d_in[1];
  const float* L   = (const float*)d_in[2];
  const float* wts = (const float*)d_in[3];
  char* wsb = (char*)d_ws;
  if (ws_size < WS_END) return;

  hipLaunchKernelGGL(gm_prep, dim3(NPREP), dim3(256), 0, stream, mu, L, wts, wsb);
  hipLaunchKernelGGL(gm_main, dim3(NMAIN), dim3(256), 0, stream, X, wsb);
  hipLaunchKernelGGL(gm_fin,  dim3(1), dim3(64), 0, stream,
                     (const double*)(wsb + WS_PART), (float*)d_out);
}